// Round 1
// baseline (540.591 us; speedup 1.0000x reference)
//
#include <hip/hip_runtime.h>
#include <math.h>

// ---------------------------------------------------------------------------
// AnchorStripeAttention  (B=2, H=W=256, NH=6, DH=32, WS=8, AWS=4)
//
// Input order (setup_inputs dict order):
//  0 qkv (2,65536,576) f32        1 anchor (2,128,128,192) f32
//  2 table (1,11,11,2) f32        3 index_a2w (16,64) i32
//  4 index_w2a (64,16) i32        5 mask_a2w (1024,16,64) f32
//  6 mask_w2a (1024,64,16) f32    7 logit_scale1 (6,1,1) f32
//  8 logit_scale2 (6,1,1) f32     9 cpb1_w1 (2,512) 10 cpb1_b1 (512)
// 11 cpb1_w2 (512,6)             12 cpb2_w1 13 cpb2_b1 14 cpb2_w2
//
// ws layout (floats):
//  [0,726)      bt1[121][6]      [768,1494)   bt2[121][6]
//  [1536,7680)  bias1[h][i*64+j] [7680,13824) bias2[h][t*16+m]
//  [13824,13836) scales: 6 for stage1, 6 for stage2
// ---------------------------------------------------------------------------

__global__ __launch_bounds__(64) void cpb_kernel(
    const float* __restrict__ table,
    const float* __restrict__ w1a, const float* __restrict__ b1a, const float* __restrict__ w2a,
    const float* __restrict__ w1b, const float* __restrict__ b1b, const float* __restrict__ w2b,
    float* __restrict__ ws)
{
    const int r   = blockIdx.x % 121;
    const int mlp = blockIdx.x / 121;
    const float* __restrict__ w1 = mlp ? w1b : w1a;
    const float* __restrict__ b1 = mlp ? b1b : b1a;
    const float* __restrict__ w2 = mlp ? w2b : w2a;
    const float t0 = table[2 * r], t1 = table[2 * r + 1];
    const int d = threadIdx.x;
    float acc[6] = {0.f, 0.f, 0.f, 0.f, 0.f, 0.f};
#pragma unroll
    for (int k = 0; k < 8; k++) {
        const int c = d + 64 * k;
        float hid = fmaxf(t0 * w1[c] + t1 * w1[512 + c] + b1[c], 0.f);
#pragma unroll
        for (int hh = 0; hh < 6; hh++) acc[hh] += hid * w2[c * 6 + hh];
    }
#pragma unroll
    for (int hh = 0; hh < 6; hh++) {
#pragma unroll
        for (int off = 32; off; off >>= 1) acc[hh] += __shfl_xor(acc[hh], off);
    }
    if (d == 0) {
#pragma unroll
        for (int hh = 0; hh < 6; hh++) ws[mlp * 768 + r * 6 + hh] = acc[hh];
    }
}

__global__ __launch_bounds__(256) void gather_bias(
    const int* __restrict__ idx1, const int* __restrict__ idx2,
    const float* __restrict__ ls1, const float* __restrict__ ls2,
    float* __restrict__ ws)
{
    const int e = blockIdx.x * 256 + threadIdx.x;
    const float* __restrict__ bt1 = ws;
    const float* __restrict__ bt2 = ws + 768;
    if (e < 6144) {
        const int h = e >> 10, rem = e & 1023;          // rem = i*64 + j
        const int t = idx1[rem];
        const float v = bt1[t * 6 + h];
        ws[1536 + e] = 16.f / (1.f + __expf(-v));
    } else if (e < 12288) {
        const int e2 = e - 6144;
        const int h = e2 >> 10, rem = e2 & 1023;        // rem = t*16 + m
        const int t = idx2[rem];
        const float v = bt2[t * 6 + h];
        ws[7680 + e2] = 16.f / (1.f + __expf(-v));
    } else if (e < 12300) {
        const int q = e - 12288;
        const float v = (q < 6) ? ls1[q] : ls2[q - 6];
        ws[13824 + q] = __expf(fminf(v, 4.605170185988092f));  // log(100)
    }
}

__global__ __launch_bounds__(64) void attn_main(
    const float* __restrict__ qkv, const float* __restrict__ anchor,
    const float* __restrict__ mask1, const float* __restrict__ mask2,
    const float* __restrict__ ws, float* __restrict__ out)
{
    __shared__ __align__(16) float v_l[64 * 36];   // V rows; reused for out staging
    __shared__ __align__(16) float a_l[16 * 36];   // normalized anchor rows
    __shared__ __align__(16) float x1_l[16 * 36];  // stage-1 output
    __shared__ float p_l[16 * 65];                 // P, stride 65 => bank-conflict-free

    const int l = threadIdx.x;
    const int bx = blockIdx.x;
    const int h = bx % 6;
    const int wid = bx / 6;
    const int b = wid >> 10;
    const int wim = wid & 1023;
    const int wy = wim >> 5, wx = wim & 31;

    const int xc = l >> 3, d4 = l & 7;

    // ---- coalesced loads: V rows and anchor rows into LDS ----
    {
        const size_t vbase = (size_t)(b * 65536 + (wy * 8) * 256 + wx * 8 + xc) * 576
                             + 384 + h * 32 + d4 * 4;
#pragma unroll
        for (int i = 0; i < 8; i++) {
            const float4 vv = *reinterpret_cast<const float4*>(qkv + vbase + (size_t)i * (256 * 576));
            *reinterpret_cast<float4*>(&v_l[(i * 8 + xc) * 36 + d4 * 4]) = vv;
        }
#pragma unroll
        for (int it = 0; it < 2; it++) {
            const int m = it * 8 + xc;
            const int ay = m >> 2, ax = m & 3;
            const size_t abase = (size_t)((b * 128 + wy * 4 + ay) * 128 + wx * 4 + ax) * 192
                                 + h * 32 + d4 * 4;
            const float4 av = *reinterpret_cast<const float4*>(anchor + abase);
            *reinterpret_cast<float4*>(&a_l[m * 36 + d4 * 4]) = av;
        }
    }

    // ---- K row per-lane + normalize (lane = window token) ----
    float kr[32];
    {
        const size_t kbase = (size_t)(b * 65536 + (wy * 8 + (l >> 3)) * 256 + wx * 8 + (l & 7)) * 576
                             + 192 + h * 32;
        float s = 0.f;
#pragma unroll
        for (int q = 0; q < 8; q++) {
            const float4 kk = *reinterpret_cast<const float4*>(qkv + kbase + q * 4);
            kr[4 * q + 0] = kk.x; kr[4 * q + 1] = kk.y; kr[4 * q + 2] = kk.z; kr[4 * q + 3] = kk.w;
            s += kk.x * kk.x + kk.y * kk.y + kk.z * kk.z + kk.w * kk.w;
        }
        const float inv = 1.f / fmaxf(sqrtf(s), 1e-12f);
#pragma unroll
        for (int dd = 0; dd < 32; dd++) kr[dd] *= inv;
    }

    __syncthreads();

    // ---- normalize anchor rows in LDS (4 lanes per row) ----
    {
        const int m = l >> 2, seg = l & 3;
        float vals[8];
        float s = 0.f;
#pragma unroll
        for (int q = 0; q < 8; q++) { vals[q] = a_l[m * 36 + seg * 8 + q]; s += vals[q] * vals[q]; }
        s += __shfl_xor(s, 1);
        s += __shfl_xor(s, 2);
        const float inv = 1.f / fmaxf(sqrtf(s), 1e-12f);
#pragma unroll
        for (int q = 0; q < 8; q++) a_l[m * 36 + seg * 8 + q] = vals[q] * inv;
    }
    __syncthreads();

    // ---- stage 1: attn1[i][lane] over 16 anchor rows, softmax across wave ----
    const float scale1 = ws[13824 + h];
    const float* __restrict__ b1p = ws + 1536 + h * 1024;
    const float* __restrict__ m1p = mask1 + wim * 1024;
    for (int i = 0; i < 16; i++) {
        float s = 0.f;
#pragma unroll
        for (int q = 0; q < 8; q++) {
            const float4 av = *reinterpret_cast<const float4*>(&a_l[i * 36 + q * 4]);
            s += av.x * kr[4 * q] + av.y * kr[4 * q + 1] + av.z * kr[4 * q + 2] + av.w * kr[4 * q + 3];
        }
        s = s * scale1 + b1p[i * 64 + l] + m1p[i * 64 + l];
        float mx = s;
#pragma unroll
        for (int off = 32; off; off >>= 1) mx = fmaxf(mx, __shfl_xor(mx, off));
        const float e = __expf(s - mx);
        float sm = e;
#pragma unroll
        for (int off = 32; off; off >>= 1) sm += __shfl_xor(sm, off);
        p_l[i * 65 + l] = e / sm;
    }

    // ---- Q row per-lane load (issue before P@V so latency hides) ----
    float qr[32];
    {
        const size_t qbase = (size_t)(b * 65536 + (wy * 8 + (l >> 3)) * 256 + wx * 8 + (l & 7)) * 576
                             + h * 32;
#pragma unroll
        for (int q = 0; q < 8; q++) {
            const float4 qq = *reinterpret_cast<const float4*>(qkv + qbase + q * 4);
            qr[4 * q + 0] = qq.x; qr[4 * q + 1] = qq.y; qr[4 * q + 2] = qq.z; qr[4 * q + 3] = qq.w;
        }
    }
    __syncthreads();

    // ---- x1 = P @ V : lane = (i = l>>2, dblk = l&3 covering 8 d's) ----
    {
        const int i = l >> 2, dblk = l & 3;
        float acc[8] = {0.f, 0.f, 0.f, 0.f, 0.f, 0.f, 0.f, 0.f};
        for (int j = 0; j < 64; j++) {
            const float p = p_l[i * 65 + j];
            const float4 va = *reinterpret_cast<const float4*>(&v_l[j * 36 + dblk * 8]);
            const float4 vb = *reinterpret_cast<const float4*>(&v_l[j * 36 + dblk * 8 + 4]);
            acc[0] += p * va.x; acc[1] += p * va.y; acc[2] += p * va.z; acc[3] += p * va.w;
            acc[4] += p * vb.x; acc[5] += p * vb.y; acc[6] += p * vb.z; acc[7] += p * vb.w;
        }
        *reinterpret_cast<float4*>(&x1_l[i * 36 + dblk * 8]) =
            make_float4(acc[0], acc[1], acc[2], acc[3]);
        *reinterpret_cast<float4*>(&x1_l[i * 36 + dblk * 8 + 4]) =
            make_float4(acc[4], acc[5], acc[6], acc[7]);
    }

    // ---- normalize qr while x1 settles ----
    {
        float s = 0.f;
#pragma unroll
        for (int dd = 0; dd < 32; dd++) s += qr[dd] * qr[dd];
        const float inv = 1.f / fmaxf(sqrtf(s), 1e-12f);
#pragma unroll
        for (int dd = 0; dd < 32; dd++) qr[dd] *= inv;
    }
    __syncthreads();

    // ---- stage 2: attn2[lane][m], in-lane softmax over 16 ----
    const float scale2 = ws[13830 + h];
    const float* __restrict__ b2p = ws + 7680 + h * 1024 + l * 16;
    const float* __restrict__ m2p = mask2 + wim * 1024 + l * 16;
    float p2[16];
    float mx2 = -3.4e38f;
#pragma unroll
    for (int m = 0; m < 16; m++) {
        float s = 0.f;
#pragma unroll
        for (int q = 0; q < 8; q++) {
            const float4 av = *reinterpret_cast<const float4*>(&a_l[m * 36 + q * 4]);
            s += av.x * qr[4 * q] + av.y * qr[4 * q + 1] + av.z * qr[4 * q + 2] + av.w * qr[4 * q + 3];
        }
        s = s * scale2 + b2p[m] + m2p[m];
        p2[m] = s;
        mx2 = fmaxf(mx2, s);
    }
    float sum = 0.f;
#pragma unroll
    for (int m = 0; m < 16; m++) { p2[m] = __expf(p2[m] - mx2); sum += p2[m]; }
    const float isum = 1.f / sum;
    float o[32];
#pragma unroll
    for (int dd = 0; dd < 32; dd++) o[dd] = 0.f;
#pragma unroll
    for (int m = 0; m < 16; m++) {
        const float p = p2[m] * isum;
#pragma unroll
        for (int q = 0; q < 8; q++) {
            const float4 xv = *reinterpret_cast<const float4*>(&x1_l[m * 36 + q * 4]);
            o[4 * q + 0] += p * xv.x; o[4 * q + 1] += p * xv.y;
            o[4 * q + 2] += p * xv.z; o[4 * q + 3] += p * xv.w;
        }
    }

    // ---- stage output through LDS (reuse v_l) for coalesced stores ----
    __syncthreads();
#pragma unroll
    for (int q = 0; q < 8; q++)
        *reinterpret_cast<float4*>(&v_l[l * 36 + q * 4]) =
            make_float4(o[4 * q], o[4 * q + 1], o[4 * q + 2], o[4 * q + 3]);
    __syncthreads();
    {
        const size_t obase = (size_t)(b * 65536 + (wy * 8) * 256 + wx * 8 + xc) * 192
                             + h * 32 + d4 * 4;
#pragma unroll
        for (int i = 0; i < 8; i++) {
            const float4 ov = *reinterpret_cast<const float4*>(&v_l[(i * 8 + xc) * 36 + d4 * 4]);
            *reinterpret_cast<float4*>(out + obase + (size_t)i * (256 * 192)) = ov;
        }
    }
}

extern "C" void kernel_launch(void* const* d_in, const int* in_sizes, int n_in,
                              void* d_out, int out_size, void* d_ws, size_t ws_size,
                              hipStream_t stream) {
    const float* qkv    = (const float*)d_in[0];
    const float* anchor = (const float*)d_in[1];
    const float* table  = (const float*)d_in[2];
    const int*   idx1   = (const int*)d_in[3];
    const int*   idx2   = (const int*)d_in[4];
    const float* mask1  = (const float*)d_in[5];
    const float* mask2  = (const float*)d_in[6];
    const float* ls1    = (const float*)d_in[7];
    const float* ls2    = (const float*)d_in[8];
    const float* w1a    = (const float*)d_in[9];
    const float* b1a    = (const float*)d_in[10];
    const float* w2a    = (const float*)d_in[11];
    const float* w1b    = (const float*)d_in[12];
    const float* b1b    = (const float*)d_in[13];
    const float* w2b    = (const float*)d_in[14];
    float* ws   = (float*)d_ws;
    float* outf = (float*)d_out;

    hipLaunchKernelGGL(cpb_kernel, dim3(242), dim3(64), 0, stream,
                       table, w1a, b1a, w2a, w1b, b1b, w2b, ws);
    hipLaunchKernelGGL(gather_bias, dim3(49), dim3(256), 0, stream,
                       idx1, idx2, ls1, ls2, ws);
    hipLaunchKernelGGL(attn_main, dim3(12288), dim3(64), 0, stream,
                       qkv, anchor, mask1, mask2, ws, outf);
}